// Round 4
// baseline (211.928 us; speedup 1.0000x reference)
//
#include <hip/hip_runtime.h>
#include <hip/hip_bf16.h>

// HT layer via bf16 MFMA, one wave per batch element, 4 waves (batches) per block.
//   Y[b] = sum_p A_p(64x64) @ X_b(64x64) @ W_p(64x64) + bias
// Step A: T^T[kl][ac] = sum_ij X^T[kl][ij] * A_p^T[ij][ac]   (M=kl,N=ac,K=ij)
// Step B: Y[ac][de]  += sum_kl T[ac][kl]  * W_p[kl][de]      (M=ac,N=de,K=kl)
// mfma_f32_16x16x32_bf16 layouts (m89/m120-verified):
//   A: A[m=lane&15][k=(lane>>4)*8+j]   B: B[k=(lane>>4)*8+j][n=lane&15]
//   C/D: col=lane&15, row=(lane>>4)*4+reg
// LDS T pitch = 68 bf16 (136 B): conflict-free for both the b64 write and
// b64 read patterns (round-3-verified: SQ_LDS_BANK_CONFLICT == 0).
// Round-4 change: software-pipelined p-loop — step A of p+1 issues between
// the tf(p) ds_reads and the step-B(p) MFMAs, so A-MFMAs hide the LDS
// round-trip latency. Single Tw buffer: writes(p+1) follow reads(p) in
// program order; the per-wave in-order DS pipe makes the WAR free.

typedef short bf16x8 __attribute__((ext_vector_type(8)));
typedef float f32x4  __attribute__((ext_vector_type(4)));

union Frag8 {
    bf16x8 v;
    unsigned int u4[4];
    uint2 u2[2];
};

static __device__ __forceinline__ unsigned int pkbf(float a, float b) {
    // v_cvt_pk_bf16_f32 on gfx950 (RNE), a -> low 16, b -> high 16
    __hip_bfloat162 h = __float22bfloat162_rn(float2{a, b});
    return *reinterpret_cast<unsigned int*>(&h);
}

static __device__ __forceinline__ unsigned short f2bf(float f) {
    unsigned int u = __float_as_uint(f);
    u = (u + 0x7FFFu + ((u >> 16) & 1u)) >> 16;   // RNE (software, precompute only)
    return (unsigned short)u;
}

// Precompute bf16 B-operand fragments of A_p^T and W_p into ws.
// Layout: frags[isW][p(8)][f=cb*2+ks (8)][lane(64)][j(8)] bf16, 64KB each.
// Frag element: B[k = ks*32 + (lane>>4)*8 + j][n = cb*16 + (lane&15)]
__global__ void ht_precompute(const float* __restrict__ F0, const float* __restrict__ F1,
                              const float* __restrict__ F2, const float* __restrict__ F3,
                              const float* __restrict__ CL, const float* __restrict__ CR,
                              unsigned short* __restrict__ frags) {
    int idx = blockIdx.x * blockDim.x + threadIdx.x;   // 0..65535
    int isW = idx >> 15;
    int r15 = idx & 32767;
    int p    = r15 >> 12;
    int f    = (r15 >> 9) & 7;
    int lane = (r15 >> 3) & 63;
    int j    = r15 & 7;
    int cb = f >> 1, ks = f & 1;
    int n = cb * 16 + (lane & 15);                // ac or de
    int k = ks * 32 + ((lane >> 4) & 3) * 8 + j;  // ij or kl
    const float* Fa = isW ? F2 : F0;
    const float* Fb = isW ? F3 : F1;
    const float* C  = isW ? CR : CL;
    int i1 = k >> 3, i2 = k & 7, o1 = n >> 3, o2 = n & 7;
    float acc = 0.f;
    for (int r = 0; r < 8; ++r) {
        float fa = Fa[(i1 * 8 + o1) * 8 + r];
        for (int s = 0; s < 8; ++s)
            acc += fa * Fb[(i2 * 8 + o2) * 8 + s] * C[(r * 8 + s) * 8 + p];
    }
    frags[(size_t)isW * 32768 + ((p * 8 + f) << 9) + lane * 8 + j] = f2bf(acc);
}

#define T_PITCH 68   // bf16 elements per row; 136 B -> conflict-free b64 (r3-verified)

__global__ __launch_bounds__(256) void ht_main(const float* __restrict__ x,
                                               const unsigned short* __restrict__ frags,
                                               const float* __restrict__ bias,
                                               float* __restrict__ out) {
    __shared__ unsigned short Tl[4 * 64 * T_PITCH];   // 34.8 KB, one slice per wave
    const int tid  = threadIdx.x;
    const int lane = tid & 63;
    const int w    = __builtin_amdgcn_readfirstlane(tid >> 6);  // wave id, scalar
    const int b    = blockIdx.x * 4 + w;                        // batch element
    unsigned short* Tw = Tl + w * (64 * T_PITCH);

    const int l15 = lane & 15;
    const int q   = lane >> 4;   // quad

    // X^T A-fragments: xf[rb][ks], element j = X^T[kl=rb*16+l15][ij=ks*32+q*8+j]
    Frag8 xf[4][2];
    const float* xb = x + ((size_t)b << 12);
#pragma unroll
    for (int rb = 0; rb < 4; ++rb)
#pragma unroll
        for (int ks = 0; ks < 2; ++ks) {
            const float* src = xb + (ks * 32 + q * 8) * 64 + rb * 16 + l15;
#pragma unroll
            for (int j = 0; j < 8; j += 2)
                xf[rb][ks].u4[j >> 1] = pkbf(src[j * 64], src[(j + 1) * 64]);
        }

    f32x4 acc[4][4];   // Y tiles: [rb over ac][cb over de]
#pragma unroll
    for (int i = 0; i < 4; ++i)
#pragma unroll
        for (int j = 0; j < 4; ++j)
            acc[i][j] = f32x4{0.f, 0.f, 0.f, 0.f};

    const unsigned short* AF = frags;          // A^T frags
    const unsigned short* WF = frags + 32768;  // W frags

    const int wr_ac = l15;        // step-A write coords
    const int wr_kl = q * 4;

    // ---- Prologue: step A for p=0 -> Tw
    {
        Frag8 af[4][2];
#pragma unroll
        for (int cb = 0; cb < 4; ++cb)
#pragma unroll
            for (int ks = 0; ks < 2; ++ks)
                af[cb][ks].v = *(const bf16x8*)(AF + (((0 * 8 + cb * 2 + ks) << 9) + lane * 8));
#pragma unroll
        for (int rb = 0; rb < 4; ++rb)
#pragma unroll
            for (int cb = 0; cb < 4; ++cb) {
                f32x4 t = f32x4{0.f, 0.f, 0.f, 0.f};
                t = __builtin_amdgcn_mfma_f32_16x16x32_bf16(xf[rb][0].v, af[cb][0].v, t, 0, 0, 0);
                t = __builtin_amdgcn_mfma_f32_16x16x32_bf16(xf[rb][1].v, af[cb][1].v, t, 0, 0, 0);
                uint2 wv;
                wv.x = pkbf(t[0], t[1]);
                wv.y = pkbf(t[2], t[3]);
                *(uint2*)(&Tw[(cb * 16 + wr_ac) * T_PITCH + rb * 16 + wr_kl]) = wv;
            }
    }

    // ---- Software-pipelined main loop over p
#pragma unroll
    for (int p = 0; p < 8; ++p) {
        // (1) issue reads of T(p)
        Frag8 tf[4][2];
#pragma unroll
        for (int rb = 0; rb < 4; ++rb)
#pragma unroll
            for (int ks = 0; ks < 2; ++ks) {
                int ac = rb * 16 + l15;
                int kl = ks * 32 + q * 8;
                tf[rb][ks].u2[0] = *(const uint2*)(&Tw[ac * T_PITCH + kl]);
                tf[rb][ks].u2[1] = *(const uint2*)(&Tw[ac * T_PITCH + kl + 4]);
            }
        // (2) issue wf(p) global loads (L2-hot)
        Frag8 wf[4][2];
#pragma unroll
        for (int cb = 0; cb < 4; ++cb)
#pragma unroll
            for (int ks = 0; ks < 2; ++ks)
                wf[cb][ks].v = *(const bf16x8*)(WF + (((p * 8 + cb * 2 + ks) << 9) + lane * 8));
        // (3) step A of p+1: independent MFMA work that hides (1)/(2) latency.
        //     Writes land after the reads in program order; per-wave in-order
        //     DS pipe makes the same-address WAR free.
        if (p < 7) {
            Frag8 af[4][2];
#pragma unroll
            for (int cb = 0; cb < 4; ++cb)
#pragma unroll
                for (int ks = 0; ks < 2; ++ks)
                    af[cb][ks].v = *(const bf16x8*)(AF + ((((p + 1) * 8 + cb * 2 + ks) << 9) + lane * 8));
#pragma unroll
            for (int rb = 0; rb < 4; ++rb)
#pragma unroll
                for (int cb = 0; cb < 4; ++cb) {
                    f32x4 t = f32x4{0.f, 0.f, 0.f, 0.f};
                    t = __builtin_amdgcn_mfma_f32_16x16x32_bf16(xf[rb][0].v, af[cb][0].v, t, 0, 0, 0);
                    t = __builtin_amdgcn_mfma_f32_16x16x32_bf16(xf[rb][1].v, af[cb][1].v, t, 0, 0, 0);
                    uint2 wv;
                    wv.x = pkbf(t[0], t[1]);
                    wv.y = pkbf(t[2], t[3]);
                    *(uint2*)(&Tw[(cb * 16 + wr_ac) * T_PITCH + rb * 16 + wr_kl]) = wv;
                }
        }
        // (4) step B of p
#pragma unroll
        for (int rb = 0; rb < 4; ++rb)
#pragma unroll
            for (int cb = 0; cb < 4; ++cb) {
                acc[rb][cb] = __builtin_amdgcn_mfma_f32_16x16x32_bf16(tf[rb][0].v, wf[cb][0].v, acc[rb][cb], 0, 0, 0);
                acc[rb][cb] = __builtin_amdgcn_mfma_f32_16x16x32_bf16(tf[rb][1].v, wf[cb][1].v, acc[rb][cb], 0, 0, 0);
            }
    }

    // ---- Epilogue: bias + store (C/D: col de=cb*16+l15, rows ac=rb*16+q*4+r)
    float* ob = out + ((size_t)b << 12);
#pragma unroll
    for (int rb = 0; rb < 4; ++rb)
#pragma unroll
        for (int cb = 0; cb < 4; ++cb) {
            int de  = cb * 16 + l15;
            int ac0 = rb * 16 + q * 4;
#pragma unroll
            for (int r = 0; r < 4; ++r) {
                int o = (ac0 + r) * 64 + de;
                ob[o] = acc[rb][cb][r] + bias[o];
            }
        }
}

extern "C" void kernel_launch(void* const* d_in, const int* in_sizes, int n_in,
                              void* d_out, int out_size, void* d_ws, size_t ws_size,
                              hipStream_t stream) {
    const float* x    = (const float*)d_in[0];
    const float* F0   = (const float*)d_in[1];
    const float* F1   = (const float*)d_in[2];
    const float* F2   = (const float*)d_in[3];
    const float* F3   = (const float*)d_in[4];
    const float* CL   = (const float*)d_in[5];
    const float* CR   = (const float*)d_in[6];
    const float* bias = (const float*)d_in[7];
    float* out = (float*)d_out;
    unsigned short* frags = (unsigned short*)d_ws;   // 128 KB

    const int B = in_sizes[0] / 4096;   // 4096

    ht_precompute<<<256, 256, 0, stream>>>(F0, F1, F2, F3, CL, CR, frags);
    ht_main<<<B / 4, 256, 0, stream>>>(x, frags, bias, out);
}